// Round 11
// baseline (198.713 us; speedup 1.0000x reference)
//
#include <hip/hip_runtime.h>
#include <math.h>

#define B_ 2
#define W_ 2048
#define C_ 1024
#define H_ 16
#define K_ 64
#define LN_EPS 1e-5f

typedef __attribute__((ext_vector_type(8))) short short8;   // 8 bf16 (4 VGPRs)
typedef __attribute__((ext_vector_type(4))) float float4v;  // MFMA C/D frag

#if __has_builtin(__builtin_amdgcn_exp2f)
#define EXP2(x) __builtin_amdgcn_exp2f(x)
#else
#define EXP2(x) exp2f(x)
#endif

__device__ inline unsigned short f2bf(float f) {  // RNE float->bf16
  unsigned u = __float_as_uint(f);
  u += 0x7fffu + ((u >> 16) & 1u);
  return (unsigned short)(u >> 16);
}

__device__ inline float max3f(float a, float b, float c) {
  return fmaxf(fmaxf(a, b), c);  // clang fuses to v_max3_f32
}

__device__ __forceinline__ void gload_lds16(const short* g, short* l) {
  __builtin_amdgcn_global_load_lds(
      (const __attribute__((address_space(1))) void*)g,
      (__attribute__((address_space(3))) void*)l, 16, 0, 0);
}

// ---------------------------------------------------------------------------
// Block-wide sum of TWO values over 256 threads (4 waves of 64)
// ---------------------------------------------------------------------------
__device__ inline float2 block_sum2(float a, float b) {
  __shared__ float2 sb[4];
  #pragma unroll
  for (int o = 32; o > 0; o >>= 1) {
    a += __shfl_down(a, o, 64);
    b += __shfl_down(b, o, 64);
  }
  int lane = threadIdx.x & 63, wid = threadIdx.x >> 6;
  if (lane == 0) { sb[wid].x = a; sb[wid].y = b; }
  __syncthreads();
  float2 r;
  r.x = (sb[0].x + sb[1].x) + (sb[2].x + sb[3].x);
  r.y = (sb[0].y + sb[1].y) + (sb[2].y + sb[3].y);
  __syncthreads();
  return r;
}

// ---------------------------------------------------------------------------
// LayerNorm -> bf16 output. One block per row; handles both seq1 and seq2.
// Single-pass: var = E[x^2] - mean^2 (inputs ~N(0,1): no cancellation risk).
// ---------------------------------------------------------------------------
__global__ __launch_bounds__(256) void ln_kernel(
    const float* __restrict__ seq1, const float* __restrict__ seq2,
    const float* __restrict__ gamma, const float* __restrict__ beta,
    short* __restrict__ x1b, short* __restrict__ x2b) {
  int row = blockIdx.x;
  const int nrows = B_ * W_;
  bool first = row < nrows;
  const float* src = first ? seq1 : seq2;
  short* dst = first ? x1b : x2b;
  int r = first ? row : row - nrows;

  const float4* p = (const float4*)(src + (size_t)r * C_);
  float4 v = p[threadIdx.x];
  float s1 = (v.x + v.y) + (v.z + v.w);
  float s2 = (v.x * v.x + v.y * v.y) + (v.z * v.z + v.w * v.w);
  float2 s = block_sum2(s1, s2);
  float mean = s.x * (1.0f / C_);
  float var = s.y * (1.0f / C_) - mean * mean;
  float rstd = rsqrtf(var + LN_EPS);

  float4 g = ((const float4*)gamma)[threadIdx.x];
  float4 b = ((const float4*)beta)[threadIdx.x];
  uint2 o;
  o.x = (unsigned)f2bf((v.x - mean) * rstd * g.x + b.x) |
        ((unsigned)f2bf((v.y - mean) * rstd * g.y + b.y) << 16);
  o.y = (unsigned)f2bf((v.z - mean) * rstd * g.z + b.z) |
        ((unsigned)f2bf((v.w - mean) * rstd * g.w + b.w) << 16);
  ((uint2*)(dst + (size_t)r * C_))[threadIdx.x] = o;
}

// ---------------------------------------------------------------------------
// Weight prep: z<3: proj [H,C,K] fp32 -> B^T bf16 [H*K rows][C cols], q
// scaled by log2(e)/sqrt(K). z==3: mixer weight plain fp32->bf16 convert.
// grid=(C/64, H, 4).
// ---------------------------------------------------------------------------
__global__ __launch_bounds__(256) void wprep_kernel(
    const float* __restrict__ qp, const float* __restrict__ kp,
    const float* __restrict__ vp, const float* __restrict__ wm,
    short* __restrict__ wqt, short* __restrict__ wkt, short* __restrict__ wvt,
    short* __restrict__ wmb) {
  int cb = blockIdx.x, h = blockIdx.y, which = blockIdx.z;
  int t = threadIdx.x;

  if (which == 3) {  // mixer weight: 1024x1024 plain convert, 256 blocks
    int blk = h * 16 + cb;                // 0..255
    #pragma unroll
    for (int j = 0; j < 4; ++j) {
      int gid = blk * 1024 + j * 256 + t; // float4 index
      float4 v = ((const float4*)wm)[gid];
      uint2 o;
      o.x = (unsigned)f2bf(v.x) | ((unsigned)f2bf(v.y) << 16);
      o.y = (unsigned)f2bf(v.z) | ((unsigned)f2bf(v.w) << 16);
      ((uint2*)wmb)[gid] = o;
    }
    return;
  }

  const float* P = (which == 0 ? qp : (which == 1 ? kp : vp)) + (size_t)h * C_ * K_;
  short* Wt = (which == 0 ? wqt : (which == 1 ? wkt : wvt));
  // q scale: 1/sqrt(64) * log2(e) so scores are in log2 units (exp2 softmax)
  float scale = (which == 0) ? 0.125f * 1.4426950408889634f : 1.0f;

  __shared__ float Ls[64][65];
  {
    int cr = t >> 2, ks = (t & 3) * 16;
    const float* src = P + (size_t)(cb * 64 + cr) * K_ + ks;
    #pragma unroll
    for (int j = 0; j < 4; ++j) {
      float4 v = *(const float4*)(src + j * 4);
      Ls[cr][ks + j * 4 + 0] = v.x; Ls[cr][ks + j * 4 + 1] = v.y;
      Ls[cr][ks + j * 4 + 2] = v.z; Ls[cr][ks + j * 4 + 3] = v.w;
    }
  }
  __syncthreads();
  int kr = t >> 2, cs = (t & 3) * 16;
  unsigned u[8];
  #pragma unroll
  for (int i = 0; i < 8; ++i) {
    float a = Ls[cs + 2 * i][kr] * scale;
    float b = Ls[cs + 2 * i + 1][kr] * scale;
    u[i] = (unsigned)f2bf(a) | ((unsigned)f2bf(b) << 16);
  }
  short* dst = Wt + ((size_t)h * 64 + kr) * C_ + cb * 64 + cs;
  uint4 p0; p0.x = u[0]; p0.y = u[1]; p0.z = u[2]; p0.w = u[3];
  uint4 p1; p1.x = u[4]; p1.y = u[5]; p1.z = u[6]; p1.w = u[7];
  *(uint4*)dst = p0;
  *(uint4*)(dst + 8) = p1;
}

// ---------------------------------------------------------------------------
// bf16 MFMA GEMM core: C[128x128] tile of A[*,1024] x Bt[*,1024]^T.
// 256 threads = 4 waves (2x2), 16x16x32 MFMA, 4x4 frags/wave, BK=64.
// global_load_lds width-16 staging; XOR-swizzled LDS (conflict-free frags).
// ---------------------------------------------------------------------------
__device__ __forceinline__ void gemm_core(
    const short* __restrict__ A, const short* __restrict__ Bt,
    int arow0, int brow0, short* As, short* Bs, float4v acc[4][4]) {
  int tid = threadIdx.x;
  int wave = tid >> 6, lane = tid & 63;
  int lr = lane >> 3, lc = lane & 7;
  int sc = lc ^ lr;                       // swizzled global chunk for staging
  int wr = wave >> 1, wc = wave & 1;
  int lg = lane >> 4, ll = lane & 15;

  #pragma unroll
  for (int mi = 0; mi < 4; ++mi)
    #pragma unroll
    for (int ni = 0; ni < 4; ++ni) {
      acc[mi][ni][0] = 0.f; acc[mi][ni][1] = 0.f;
      acc[mi][ni][2] = 0.f; acc[mi][ni][3] = 0.f;
    }

  for (int k0 = 0; k0 < C_; k0 += 64) {
    __syncthreads();
    #pragma unroll
    for (int j = 0; j < 4; ++j) {
      int seg = wave * 4 + j;            // 8-row segment of the 128-row tile
      int r = seg * 8 + lr;
      gload_lds16(A + (size_t)(arow0 + r) * C_ + k0 + sc * 8, As + seg * 512);
      gload_lds16(Bt + (size_t)(brow0 + r) * C_ + k0 + sc * 8, Bs + seg * 512);
    }
    __syncthreads();
    #pragma unroll
    for (int kc = 0; kc < 2; ++kc) {
      int cc = kc * 4 + lg;
      short8 af[4], bf[4];
      #pragma unroll
      for (int mi = 0; mi < 4; ++mi) {
        int m = wr * 64 + mi * 16 + ll;
        af[mi] = *(const short8*)&As[m * 64 + ((cc ^ (m & 7)) << 3)];
      }
      #pragma unroll
      for (int ni = 0; ni < 4; ++ni) {
        int n = wc * 64 + ni * 16 + ll;
        bf[ni] = *(const short8*)&Bs[n * 64 + ((cc ^ (n & 7)) << 3)];
      }
      #pragma unroll
      for (int mi = 0; mi < 4; ++mi)
        #pragma unroll
        for (int ni = 0; ni < 4; ++ni)
          acc[mi][ni] = __builtin_amdgcn_mfma_f32_16x16x32_bf16(
              af[mi], bf[ni], acc[mi][ni], 0, 0, 0);
    }
  }
}

// ---------------------------------------------------------------------------
// 64-row variant for the mixer: C[64x128] tile. (round-4 proven)
// ---------------------------------------------------------------------------
__device__ __forceinline__ void gemm_core64(
    const short* __restrict__ A, const short* __restrict__ Bt,
    int arow0, int brow0, short* As, short* Bs, float4v acc[2][4]) {
  int tid = threadIdx.x;
  int wave = tid >> 6, lane = tid & 63;
  int lr = lane >> 3, lc = lane & 7;
  int sc = lc ^ lr;                       // swizzled global chunk for staging
  int wr = wave >> 1, wc = wave & 1;
  int lg = lane >> 4, ll = lane & 15;

  #pragma unroll
  for (int mi = 0; mi < 2; ++mi)
    #pragma unroll
    for (int ni = 0; ni < 4; ++ni) {
      acc[mi][ni][0] = 0.f; acc[mi][ni][1] = 0.f;
      acc[mi][ni][2] = 0.f; acc[mi][ni][3] = 0.f;
    }

  for (int k0 = 0; k0 < C_; k0 += 64) {
    __syncthreads();
    #pragma unroll
    for (int j = 0; j < 2; ++j) {        // A: 64 rows = 8 segs of 8
      int seg = wave * 2 + j;
      int r = seg * 8 + lr;
      gload_lds16(A + (size_t)(arow0 + r) * C_ + k0 + sc * 8, As + seg * 512);
    }
    #pragma unroll
    for (int j = 0; j < 4; ++j) {        // B: 128 rows = 16 segs
      int seg = wave * 4 + j;
      int r = seg * 8 + lr;
      gload_lds16(Bt + (size_t)(brow0 + r) * C_ + k0 + sc * 8, Bs + seg * 512);
    }
    __syncthreads();
    #pragma unroll
    for (int kc = 0; kc < 2; ++kc) {
      int cc = kc * 4 + lg;
      short8 af[2], bf[4];
      #pragma unroll
      for (int mi = 0; mi < 2; ++mi) {
        int m = wr * 32 + mi * 16 + ll;
        af[mi] = *(const short8*)&As[m * 64 + ((cc ^ (m & 7)) << 3)];
      }
      #pragma unroll
      for (int ni = 0; ni < 4; ++ni) {
        int n = wc * 64 + ni * 16 + ll;
        bf[ni] = *(const short8*)&Bs[n * 64 + ((cc ^ (n & 7)) << 3)];
      }
      #pragma unroll
      for (int mi = 0; mi < 2; ++mi)
        #pragma unroll
        for (int ni = 0; ni < 4; ++ni)
          acc[mi][ni] = __builtin_amdgcn_mfma_f32_16x16x32_bf16(
              af[mi], bf[ni], acc[mi][ni], 0, 0, 0);
    }
  }
}

// ---------------------------------------------------------------------------
// QKV GEMMs, fused in grid.z: z=0 Q=x1@Wq^T, z=1 K=x2@Wk^T,
// z=2 V^T = Wv x2^T. grid=(32,8,3). LDS-staged coalesced epilogue.
// ---------------------------------------------------------------------------
__global__ __launch_bounds__(256, 3) void gemm_qkv_kernel(
    const short* __restrict__ x1b, const short* __restrict__ x2b,
    const short* __restrict__ wqt, const short* __restrict__ wkt,
    const short* __restrict__ wvt,
    short* __restrict__ qb, short* __restrict__ kb, short* __restrict__ vtb) {
  __shared__ short smem[128 * 132];       // 33792 B; As/Bs overlay + Ct
  short* As = smem;                       // 128*64 = 8192 shorts
  short* Bs = smem + 8192;                // 128*64
  int z = blockIdx.z;
  const short *A, *Bt;
  int arow0, brow0;
  if (z == 0)      { A = x1b; Bt = wqt; arow0 = blockIdx.x * 128; brow0 = blockIdx.y * 128; }
  else if (z == 1) { A = x2b; Bt = wkt; arow0 = blockIdx.x * 128; brow0 = blockIdx.y * 128; }
  else             { A = wvt; Bt = x2b; arow0 = blockIdx.y * 128; brow0 = blockIdx.x * 128; }

  float4v acc[4][4];
  gemm_core(A, Bt, arow0, brow0, As, Bs, acc);

  int tid = threadIdx.x;
  int wave = tid >> 6, lane = tid & 63;
  int wr = wave >> 1, wc = wave & 1, lg = lane >> 4, ll = lane & 15;

  __syncthreads();  // all waves done reading As/Bs; reuse smem as Ct[128][132]
  #pragma unroll
  for (int mi = 0; mi < 4; ++mi)
    #pragma unroll
    for (int ni = 0; ni < 4; ++ni)
      #pragma unroll
      for (int r2 = 0; r2 < 4; ++r2)
        smem[(wr * 64 + mi * 16 + lg * 4 + r2) * 132 + wc * 64 + ni * 16 + ll] =
            (short)f2bf(acc[mi][ni][r2]);
  __syncthreads();

  if (z <= 1) {
    short* O = (z == 0) ? qb : kb;
    int hb = brow0 >> 6;                  // n = brow0+nl -> h = hb + (nl>>6)
    #pragma unroll
    for (int p = 0; p < 8; ++p) {
      int r = p * 16 + (tid >> 4);        // local m row
      int seg = tid & 15;                 // 16B segment within the 256B row
      int m = arow0 + r, b = m >> 11, w = m & (W_ - 1);
      int half = seg >> 3, kkseg = seg & 7;
      const short* src = &smem[r * 132 + seg * 8];
      uint2 lo = *(const uint2*)src;
      uint2 hi = *(const uint2*)(src + 4);
      uint4 val; val.x = lo.x; val.y = lo.y; val.z = hi.x; val.w = hi.y;
      *(uint4*)(O + ((size_t)(b * H_ + hb + half) * W_ + w) * K_ + kkseg * 8) = val;
    }
  } else {
    int b = brow0 >> 11, w0 = brow0 & (W_ - 1);  // brow0 128-aligned -> const
    #pragma unroll
    for (int p = 0; p < 8; ++p) {
      int r = p * 16 + (tid >> 4);        // local m row (= h*64+kk space)
      int seg = tid & 15;
      int mg = arow0 + r, h = mg >> 6, kk = mg & 63;
      const short* src = &smem[r * 132 + seg * 8];
      uint2 lo = *(const uint2*)src;
      uint2 hi = *(const uint2*)(src + 4);
      uint4 val; val.x = lo.x; val.y = lo.y; val.z = hi.x; val.w = hi.y;
      *(uint4*)(vtb + ((size_t)(b * H_ + h) * K_ + kk) * W_ + w0 + seg * 8) = val;
    }
  }
}

// ---------------------------------------------------------------------------
// Mixer GEMM: out[4096,1024] fp32 = attnb @ wmb^T + bias. grid=(64,8)=512
// blocks = 2/CU. (round-4 proven)
// ---------------------------------------------------------------------------
__global__ __launch_bounds__(256, 3) void gemm_mix_kernel(
    const short* __restrict__ attnb, const short* __restrict__ wmb,
    const float* __restrict__ bias, float* __restrict__ out) {
  __shared__ short As[64 * 64], Bs[128 * 64];
  int arow0 = blockIdx.x * 64, brow0 = blockIdx.y * 128;
  float4v acc[2][4];
  gemm_core64(attnb, wmb, arow0, brow0, As, Bs, acc);

  int wave = threadIdx.x >> 6, lane = threadIdx.x & 63;
  int wr = wave >> 1, wc = wave & 1, lg = lane >> 4, ll = lane & 15;
  #pragma unroll
  for (int mi = 0; mi < 2; ++mi)
    #pragma unroll
    for (int ni = 0; ni < 4; ++ni) {
      int n = brow0 + wc * 64 + ni * 16 + ll;
      float bv = bias[n];
      #pragma unroll
      for (int r2 = 0; r2 < 4; ++r2) {
        int m = arow0 + wr * 32 + mi * 16 + lg * 4 + r2;
        out[(size_t)m * C_ + n] = acc[mi][ni][r2] + bv;
      }
    }
}

// ---------------------------------------------------------------------------
// Causal flash attention — 2x2 wave decomposition to halve LDS reads.
// Wave w = qhalf*2 + khalf owns 32 keys (khalf) x 32 q (qhalf) of the
// 64x64 tile: K/V tile LDS reads per wave HALVE (4+4 b128 vs 8+8; block
// total 72 -> 40 b128/iter ~= 24us -> 13us of LDS-read pipe per CU).
// Same 16x16x32 MFMAs, same chunk swizzles, same R10 single-barrier
// schedule (vmcnt(0) lgkmcnt(0) + barrier at top; STAGE after; spill-robust).
// Per-wave partial (O[64c x 32q], m[2], l[2]) merged across khalf pairs at
// the end via LDS overlay on the dead K/V buffers (scaled sum, 2 barriers).
// NaN guard: m init = -1e37 (finite) so fully-masked wave-quadrants (e.g.
// khalf=1,qhalf=0 on the diagonal tile, or qt=0) yield scale=exp2(-1e37-m*)
// = 0 partials instead of NaN; mask value stays -INFINITY so exp2(-inf)=0.
// ---------------------------------------------------------------------------
__global__ __launch_bounds__(256, 3) void attn_mfma_kernel(
    const short* __restrict__ q, const short* __restrict__ k,
    const short* __restrict__ vt, short* __restrict__ out) {
  int bh = blockIdx.x;                    // 0..31
  int b = bh >> 4, h = bh & 15;
  int s = blockIdx.y;
  int qt = (s < 16) ? (31 - s) : (s - 16);  // balanced heavy/light pairing
  int wave = threadIdx.x >> 6;
  int khalf = wave & 1, qhalf = wave >> 1;
  int lane = threadIdx.x & 63;
  int lg = lane >> 4, ll = lane & 15;

  // LDS: Ks 2x4096 + Vs 2x4096 + Ps 4x1280 shorts = 43008 B (3 blocks/CU).
  // Merge overlays the first 34816 B after the loop.
  __shared__ __align__(16) long long smemU[5376];
  short* smem = (short*)smemU;
  short* KsB = smem;                      // [buf][key64][chan chunks]
  short* VsB = smem + 8192;               // [buf][chan64][key chunks]
  short* myP = smem + 16384 + wave * 1280;  // [q' 32][stride 40]
  __shared__ float mS[4][2][16], lS[4][2][16];

  const short* qp = q + (size_t)bh * W_ * K_;
  const short* kp = k + (size_t)bh * W_ * K_;
  const short* vb = vt + (size_t)bh * K_ * W_;

  // Q B-frags for this wave's 32 q rows (2 blocks of 16)
  short8 aq[2][2];                        // [qb][kc]
  #pragma unroll
  for (int qb2 = 0; qb2 < 2; ++qb2)
    #pragma unroll
    for (int kc = 0; kc < 2; ++kc)
      aq[qb2][kc] = *(const short8*)(
          qp + (size_t)(qt * 64 + qhalf * 32 + qb2 * 16 + ll) * K_ + kc * 32 + lg * 8);

  short8 ones;                            // bf16 1.0 x8, A-frag for l-sum MFMA
  #pragma unroll
  for (int i = 0; i < 8; ++i) ones[i] = (short)0x3F80;

  float4v o[4][2];                        // [ct][qb]: O[chan ct*16+lg*4+r][q qb*16+ll]
  #pragma unroll
  for (int ct = 0; ct < 4; ++ct)
    #pragma unroll
    for (int qb2 = 0; qb2 < 2; ++qb2) {
      o[ct][qb2][0] = 0.f; o[ct][qb2][1] = 0.f;
      o[ct][qb2][2] = 0.f; o[ct][qb2][3] = 0.f;
    }
  float4v lsum[2];
  lsum[0][0] = 0.f; lsum[0][1] = 0.f; lsum[0][2] = 0.f; lsum[0][3] = 0.f;
  lsum[1][0] = 0.f; lsum[1][1] = 0.f; lsum[1][2] = 0.f; lsum[1][3] = 0.f;
  float m0 = -1e37f, m1 = -1e37f;         // finite init (see header comment)

  int nkt = qt + 1;

  #define STAGE(kt, buf)                                                     \
    {                                                                        \
      const short* kbase = kp + (size_t)(kt) * 64 * K_;                      \
      const short* vbase = vb + (kt) * 64;                                   \
      _Pragma("unroll")                                                      \
      for (int j = 0; j < 2; ++j) {                                          \
        int sdx = j * 256 + (int)threadIdx.x;                                \
        int mm = sdx >> 3, c7 = sdx & 7;                                     \
        int gc = c7 ^ (mm & 7);                                              \
        gload_lds16(kbase + (size_t)mm * K_ + gc * 8, KsB + (buf) * 4096 + sdx * 8); \
        gload_lds16(vbase + (size_t)mm * W_ + gc * 8, VsB + (buf) * 4096 + sdx * 8); \
      }                                                                      \
    }

  STAGE(0, 0);
  for (int kt = 0; kt < nkt; ++kt) {
    int cur = kt & 1;
    // single rendezvous: own loads landed, own LDS reads drained, barrier;
    // STAGE issues only after it (prefetch distance = one full body).
    asm volatile("s_waitcnt vmcnt(0) lgkmcnt(0)\ns_barrier" ::: "memory");
    if (kt + 1 < nkt) STAGE(kt + 1, cur ^ 1);

    // ---- S^T = K.Q^T over this wave's 32 keys x 32 q ----
    float4v st[2][2];                     // [kb][qb]
    __builtin_amdgcn_s_setprio(1);
    #pragma unroll
    for (int kb2 = 0; kb2 < 2; ++kb2) {
      st[kb2][0][0] = 0.f; st[kb2][0][1] = 0.f; st[kb2][0][2] = 0.f; st[kb2][0][3] = 0.f;
      st[kb2][1][0] = 0.f; st[kb2][1][1] = 0.f; st[kb2][1][2] = 0.f; st[kb2][1][3] = 0.f;
      int n = khalf * 32 + kb2 * 16 + ll; // key row in K-tile
      #pragma unroll
      for (int kc = 0; kc < 2; ++kc) {
        int cc = kc * 4 + lg;
        short8 ak = *(const short8*)&KsB[cur * 4096 + n * 64 + ((cc ^ (n & 7)) << 3)];
        st[kb2][0] = __builtin_amdgcn_mfma_f32_16x16x32_bf16(ak, aq[0][kc], st[kb2][0], 0, 0, 0);
        st[kb2][1] = __builtin_amdgcn_mfma_f32_16x16x32_bf16(ak, aq[1][kc], st[kb2][1], 0, 0, 0);
      }
    }
    __builtin_amdgcn_s_setprio(0);

    // ---- V^T frags (A operand of PV): 4 reads, this wave's key-half only ----
    short8 bv[4];
    #pragma unroll
    for (int ct = 0; ct < 4; ++ct) {
      int c = ct * 16 + ll;
      int cc = khalf * 4 + lg;            // chunk of this key-half
      bv[ct] = *(const short8*)&VsB[cur * 4096 + c * 64 + ((cc ^ (c & 7)) << 3)];
    }

    if (kt == qt) {  // diagonal tile: causal mask (key > q), both in-tile
      #pragma unroll
      for (int kb2 = 0; kb2 < 2; ++kb2) {
        int keyb = khalf * 32 + kb2 * 16 + lg * 4;
        #pragma unroll
        for (int r = 0; r < 4; ++r) {
          int key = keyb + r;
          if (key > qhalf * 32 + ll) st[kb2][0][r] = -INFINITY;
          if (key > qhalf * 32 + 16 + ll) st[kb2][1][r] = -INFINITY;
        }
      }
    }

    // ---- row max per qb (8 local values + lg-reduce) ----
    float lm0 = fmaxf(max3f(st[0][0][0], st[0][0][1], st[0][0][2]),
                      fmaxf(max3f(st[0][0][3], st[1][0][0], st[1][0][1]),
                            max3f(st[1][0][2], st[1][0][3], -INFINITY)));
    float lm1 = fmaxf(max3f(st[0][1][0], st[0][1][1], st[0][1][2]),
                      fmaxf(max3f(st[0][1][3], st[1][1][0], st[1][1][1]),
                            max3f(st[1][1][2], st[1][1][3], -INFINITY)));
    lm0 = fmaxf(lm0, __shfl_xor(lm0, 16, 64));
    lm0 = fmaxf(lm0, __shfl_xor(lm0, 32, 64));
    lm1 = fmaxf(lm1, __shfl_xor(lm1, 16, 64));
    lm1 = fmaxf(lm1, __shfl_xor(lm1, 32, 64));
    if (!__all((lm0 <= m0 + 8.f) && (lm1 <= m1 + 8.f))) {
      float nm0 = fmaxf(m0, lm0), nm1 = fmaxf(m1, lm1);
      float al0 = EXP2(m0 - nm0), al1 = EXP2(m1 - nm1);
      m0 = nm0; m1 = nm1;
      lsum[0][0] *= al0; lsum[0][1] *= al0; lsum[0][2] *= al0; lsum[0][3] *= al0;
      lsum[1][0] *= al1; lsum[1][1] *= al1; lsum[1][2] *= al1; lsum[1][3] *= al1;
      #pragma unroll
      for (int ct = 0; ct < 4; ++ct) {
        o[ct][0][0] *= al0; o[ct][0][1] *= al0; o[ct][0][2] *= al0; o[ct][0][3] *= al0;
        o[ct][1][0] *= al1; o[ct][1][1] *= al1; o[ct][1][2] *= al1; o[ct][1][3] *= al1;
      }
    }

    // ---- P = exp2(S - m) -> bf16 -> wave-private LDS [q'][key j] ----
    #pragma unroll
    for (int kb2 = 0; kb2 < 2; ++kb2) {
      {
        float e0 = EXP2(st[kb2][0][0] - m0), e1 = EXP2(st[kb2][0][1] - m0);
        float e2 = EXP2(st[kb2][0][2] - m0), e3 = EXP2(st[kb2][0][3] - m0);
        uint2 w;
        w.x = (unsigned)f2bf(e0) | ((unsigned)f2bf(e1) << 16);
        w.y = (unsigned)f2bf(e2) | ((unsigned)f2bf(e3) << 16);
        *(uint2*)(myP + ll * 40 + kb2 * 16 + lg * 4) = w;
      }
      {
        float e0 = EXP2(st[kb2][1][0] - m1), e1 = EXP2(st[kb2][1][1] - m1);
        float e2 = EXP2(st[kb2][1][2] - m1), e3 = EXP2(st[kb2][1][3] - m1);
        uint2 w;
        w.x = (unsigned)f2bf(e0) | ((unsigned)f2bf(e1) << 16);
        w.y = (unsigned)f2bf(e2) | ((unsigned)f2bf(e3) << 16);
        *(uint2*)(myP + (16 + ll) * 40 + kb2 * 16 + lg * 4) = w;
      }
    }
    __builtin_amdgcn_s_waitcnt(0xC07F);   // lgkmcnt(0), wave-private
    short8 bp0 = *(const short8*)(myP + ll * 40 + lg * 8);
    short8 bp1 = *(const short8*)(myP + (16 + ll) * 40 + lg * 8);

    // ---- O += V^T.P ; l += ones.P (K=32 over this wave's keys) ----
    __builtin_amdgcn_s_setprio(1);
    lsum[0] = __builtin_amdgcn_mfma_f32_16x16x32_bf16(ones, bp0, lsum[0], 0, 0, 0);
    lsum[1] = __builtin_amdgcn_mfma_f32_16x16x32_bf16(ones, bp1, lsum[1], 0, 0, 0);
    #pragma unroll
    for (int ct = 0; ct < 4; ++ct) {
      o[ct][0] = __builtin_amdgcn_mfma_f32_16x16x32_bf16(bv[ct], bp0, o[ct][0], 0, 0, 0);
      o[ct][1] = __builtin_amdgcn_mfma_f32_16x16x32_bf16(bv[ct], bp1, o[ct][1], 0, 0, 0);
    }
    __builtin_amdgcn_s_setprio(0);
    // no trailing barrier: next top rendezvous fences buffer reuse
  }
  #undef STAGE

  // ---- cross-khalf merge: O_final = sum_w O_w * exp2(m_w - m*) ----
  __syncthreads();                        // drain; Ks/Vs/Ps now dead
  if (lg == 0) {
    mS[wave][0][ll] = m0; mS[wave][1][ll] = m1;
    lS[wave][0][ll] = lsum[0][0]; lS[wave][1][ll] = lsum[1][0];
  }
  __syncthreads();
  int pw = wave ^ 1;                      // partner: same qhalf, other khalf
  float pm0 = mS[pw][0][ll], pm1 = mS[pw][1][ll];
  float pl0 = lS[pw][0][ll], pl1 = lS[pw][1][ll];
  float ms0 = fmaxf(m0, pm0), ms1 = fmaxf(m1, pm1);
  float sc0 = EXP2(m0 - ms0), sc1 = EXP2(m1 - ms1);
  float lf0 = lsum[0][0] * sc0 + pl0 * EXP2(pm0 - ms0);
  float lf1 = lsum[1][0] * sc1 + pl1 * EXP2(pm1 - ms1);

  // write scaled partials: buf[qhalf*2+khalf][q' 32][68 floats]
  float* mb = (float*)smemU;
  float* myb = mb + (size_t)(wave * 2176);
  #pragma unroll
  for (int ct = 0; ct < 4; ++ct)
    #pragma unroll
    for (int qb2 = 0; qb2 < 2; ++qb2) {
      float sc = qb2 ? sc1 : sc0;
      float4v v;
      v[0] = o[ct][qb2][0] * sc; v[1] = o[ct][qb2][1] * sc;
      v[2] = o[ct][qb2][2] * sc; v[3] = o[ct][qb2][3] * sc;
      *(float4v*)&myb[(qb2 * 16 + ll) * 68 + ct * 16 + lg * 4] = v;
    }
  __syncthreads();

  // finalize: this wave handles chans [khalf*32, +32) of its q-half
  float* b0 = mb + (size_t)((qhalf * 2 + 0) * 2176);
  float* b1 = mb + (size_t)((qhalf * 2 + 1) * 2176);
  #pragma unroll
  for (int qb2 = 0; qb2 < 2; ++qb2) {
    float invl = 1.0f / (qb2 ? lf1 : lf0);
    int qrow = qt * 64 + qhalf * 32 + qb2 * 16 + ll;
    size_t orow = ((size_t)(b * W_ + qrow)) * C_ + h * K_;
    #pragma unroll
    for (int ct2 = 0; ct2 < 2; ++ct2) {
      int chan = khalf * 32 + ct2 * 16 + lg * 4;
      int idx = (qb2 * 16 + ll) * 68 + chan;
      float4v vA = *(const float4v*)&b0[idx];
      float4v vB = *(const float4v*)&b1[idx];
      uint2 w;
      w.x = (unsigned)f2bf((vA[0] + vB[0]) * invl) |
            ((unsigned)f2bf((vA[1] + vB[1]) * invl) << 16);
      w.y = (unsigned)f2bf((vA[2] + vB[2]) * invl) |
            ((unsigned)f2bf((vA[3] + vB[3]) * invl) << 16);
      *(uint2*)(out + orow + chan) = w;
    }
  }
}

// ---------------------------------------------------------------------------
extern "C" void kernel_launch(void* const* d_in, const int* in_sizes, int n_in,
                              void* d_out, int out_size, void* d_ws, size_t ws_size,
                              hipStream_t stream) {
  const float* seq1  = (const float*)d_in[0];
  const float* seq2  = (const float*)d_in[1];
  const float* gamma = (const float*)d_in[2];
  const float* beta  = (const float*)d_in[3];
  const float* qp    = (const float*)d_in[4];
  const float* kp    = (const float*)d_in[5];
  const float* vp    = (const float*)d_in[6];
  const float* wm    = (const float*)d_in[7];
  const float* mb    = (const float*)d_in[8];
  float* out = (float*)d_out;

  char* ws = (char*)d_ws;
  const size_t NROW = (size_t)B_ * W_;               // 4096
  const size_t XB = NROW * C_ * sizeof(short);       // 8 MB bf16 activation buf
  const size_t WB = (size_t)C_ * C_ * sizeof(short); // 2 MB bf16 weight buf
  short* x1b = (short*)(ws);
  short* x2b = (short*)(ws + XB);
  short* qb  = (short*)(ws + 2 * XB);
  short* kb  = (short*)(ws + 3 * XB);
  short* vtb = (short*)(ws + 4 * XB);
  short* wqt = (short*)(ws + 5 * XB);
  short* wkt = (short*)(ws + 5 * XB + WB);
  short* wvt = (short*)(ws + 5 * XB + 2 * WB);
  short* wmb = (short*)(ws + 5 * XB + 3 * WB);
  short* attnb = (short*)(ws + 5 * XB + 4 * WB);

  wprep_kernel<<<dim3(C_ / 64, H_, 4), dim3(256), 0, stream>>>(
      qp, kp, vp, wm, wqt, wkt, wvt, wmb);
  ln_kernel<<<dim3(2 * (unsigned)NROW), dim3(256), 0, stream>>>(
      seq1, seq2, gamma, beta, x1b, x2b);
  gemm_qkv_kernel<<<dim3(32, 8, 3), dim3(256), 0, stream>>>(
      x1b, x2b, wqt, wkt, wvt, qb, kb, vtb);
  attn_mfma_kernel<<<dim3(32, 32), dim3(256), 0, stream>>>(
      qb, kb, vtb, attnb);
  gemm_mix_kernel<<<dim3(64, 8), dim3(256), 0, stream>>>(attnb, wmb, mb, out);
}

// Round 14
// 192.680 us; speedup vs baseline: 1.0313x; 1.0313x over previous
//
#include <hip/hip_runtime.h>
#include <math.h>

#define B_ 2
#define W_ 2048
#define C_ 1024
#define H_ 16
#define K_ 64
#define LN_EPS 1e-5f

typedef __attribute__((ext_vector_type(8))) short short8;   // 8 bf16 (4 VGPRs)
typedef __attribute__((ext_vector_type(4))) float float4v;  // MFMA C/D frag

#if __has_builtin(__builtin_amdgcn_exp2f)
#define EXP2(x) __builtin_amdgcn_exp2f(x)
#else
#define EXP2(x) exp2f(x)
#endif

__device__ inline unsigned short f2bf(float f) {  // RNE float->bf16
  unsigned u = __float_as_uint(f);
  u += 0x7fffu + ((u >> 16) & 1u);
  return (unsigned short)(u >> 16);
}

__device__ inline float max3f(float a, float b, float c) {
  return fmaxf(fmaxf(a, b), c);  // clang fuses to v_max3_f32
}

__device__ __forceinline__ void gload_lds16(const short* g, short* l) {
  __builtin_amdgcn_global_load_lds(
      (const __attribute__((address_space(1))) void*)g,
      (__attribute__((address_space(3))) void*)l, 16, 0, 0);
}

// ---------------------------------------------------------------------------
// Block-wide sum of TWO values over 256 threads (4 waves of 64) — one
// barrier pair instead of two (single-pass LN mean/var).
// ---------------------------------------------------------------------------
__device__ inline float2 block_sum2(float a, float b) {
  __shared__ float2 sb[4];
  #pragma unroll
  for (int o = 32; o > 0; o >>= 1) {
    a += __shfl_down(a, o, 64);
    b += __shfl_down(b, o, 64);
  }
  int lane = threadIdx.x & 63, wid = threadIdx.x >> 6;
  if (lane == 0) { sb[wid].x = a; sb[wid].y = b; }
  __syncthreads();
  float2 r;
  r.x = (sb[0].x + sb[1].x) + (sb[2].x + sb[3].x);
  r.y = (sb[0].y + sb[1].y) + (sb[2].y + sb[3].y);
  __syncthreads();
  return r;
}

// ---------------------------------------------------------------------------
// LayerNorm -> bf16 output. One block per row; handles both seq1 and seq2.
// Single-pass: var = E[x^2] - mean^2 (inputs ~N(0,1): no cancellation risk).
// ---------------------------------------------------------------------------
__global__ __launch_bounds__(256) void ln_kernel(
    const float* __restrict__ seq1, const float* __restrict__ seq2,
    const float* __restrict__ gamma, const float* __restrict__ beta,
    short* __restrict__ x1b, short* __restrict__ x2b) {
  int row = blockIdx.x;
  const int nrows = B_ * W_;
  bool first = row < nrows;
  const float* src = first ? seq1 : seq2;
  short* dst = first ? x1b : x2b;
  int r = first ? row : row - nrows;

  const float4* p = (const float4*)(src + (size_t)r * C_);
  float4 v = p[threadIdx.x];
  float s1 = (v.x + v.y) + (v.z + v.w);
  float s2 = (v.x * v.x + v.y * v.y) + (v.z * v.z + v.w * v.w);
  float2 s = block_sum2(s1, s2);
  float mean = s.x * (1.0f / C_);
  float var = s.y * (1.0f / C_) - mean * mean;
  float rstd = rsqrtf(var + LN_EPS);

  float4 g = ((const float4*)gamma)[threadIdx.x];
  float4 b = ((const float4*)beta)[threadIdx.x];
  uint2 o;
  o.x = (unsigned)f2bf((v.x - mean) * rstd * g.x + b.x) |
        ((unsigned)f2bf((v.y - mean) * rstd * g.y + b.y) << 16);
  o.y = (unsigned)f2bf((v.z - mean) * rstd * g.z + b.z) |
        ((unsigned)f2bf((v.w - mean) * rstd * g.w + b.w) << 16);
  ((uint2*)(dst + (size_t)r * C_))[threadIdx.x] = o;
}

// ---------------------------------------------------------------------------
// Weight prep: z<3: proj [H,C,K] fp32 -> B^T bf16 [H*K rows][C cols], q
// scaled by log2(e)/sqrt(K). z==3: mixer weight plain fp32->bf16 convert.
// grid=(C/64, H, 4).
// ---------------------------------------------------------------------------
__global__ __launch_bounds__(256) void wprep_kernel(
    const float* __restrict__ qp, const float* __restrict__ kp,
    const float* __restrict__ vp, const float* __restrict__ wm,
    short* __restrict__ wqt, short* __restrict__ wkt, short* __restrict__ wvt,
    short* __restrict__ wmb) {
  int cb = blockIdx.x, h = blockIdx.y, which = blockIdx.z;
  int t = threadIdx.x;

  if (which == 3) {  // mixer weight: 1024x1024 plain convert, 256 blocks
    int blk = h * 16 + cb;                // 0..255
    #pragma unroll
    for (int j = 0; j < 4; ++j) {
      int gid = blk * 1024 + j * 256 + t; // float4 index
      float4 v = ((const float4*)wm)[gid];
      uint2 o;
      o.x = (unsigned)f2bf(v.x) | ((unsigned)f2bf(v.y) << 16);
      o.y = (unsigned)f2bf(v.z) | ((unsigned)f2bf(v.w) << 16);
      ((uint2*)wmb)[gid] = o;
    }
    return;
  }

  const float* P = (which == 0 ? qp : (which == 1 ? kp : vp)) + (size_t)h * C_ * K_;
  short* Wt = (which == 0 ? wqt : (which == 1 ? wkt : wvt));
  // q scale: 1/sqrt(64) * log2(e) so scores are in log2 units (exp2 softmax)
  float scale = (which == 0) ? 0.125f * 1.4426950408889634f : 1.0f;

  __shared__ float Ls[64][65];
  {
    int cr = t >> 2, ks = (t & 3) * 16;
    const float* src = P + (size_t)(cb * 64 + cr) * K_ + ks;
    #pragma unroll
    for (int j = 0; j < 4; ++j) {
      float4 v = *(const float4*)(src + j * 4);
      Ls[cr][ks + j * 4 + 0] = v.x; Ls[cr][ks + j * 4 + 1] = v.y;
      Ls[cr][ks + j * 4 + 2] = v.z; Ls[cr][ks + j * 4 + 3] = v.w;
    }
  }
  __syncthreads();
  int kr = t >> 2, cs = (t & 3) * 16;
  unsigned u[8];
  #pragma unroll
  for (int i = 0; i < 8; ++i) {
    float a = Ls[cs + 2 * i][kr] * scale;
    float b = Ls[cs + 2 * i + 1][kr] * scale;
    u[i] = (unsigned)f2bf(a) | ((unsigned)f2bf(b) << 16);
  }
  short* dst = Wt + ((size_t)h * 64 + kr) * C_ + cb * 64 + cs;
  uint4 p0; p0.x = u[0]; p0.y = u[1]; p0.z = u[2]; p0.w = u[3];
  uint4 p1; p1.x = u[4]; p1.y = u[5]; p1.z = u[6]; p1.w = u[7];
  *(uint4*)dst = p0;
  *(uint4*)(dst + 8) = p1;
}

// ---------------------------------------------------------------------------
// bf16 MFMA GEMM core: C[128x128] tile of A[*,1024] x Bt[*,1024]^T.
// 256 threads = 4 waves (2x2), 16x16x32 MFMA, 4x4 frags/wave, BK=64.
// global_load_lds width-16 staging; XOR-swizzled LDS (conflict-free frags).
// ---------------------------------------------------------------------------
__device__ __forceinline__ void gemm_core(
    const short* __restrict__ A, const short* __restrict__ Bt,
    int arow0, int brow0, short* As, short* Bs, float4v acc[4][4]) {
  int tid = threadIdx.x;
  int wave = tid >> 6, lane = tid & 63;
  int lr = lane >> 3, lc = lane & 7;
  int sc = lc ^ lr;                       // swizzled global chunk for staging
  int wr = wave >> 1, wc = wave & 1;
  int lg = lane >> 4, ll = lane & 15;

  #pragma unroll
  for (int mi = 0; mi < 4; ++mi)
    #pragma unroll
    for (int ni = 0; ni < 4; ++ni) {
      acc[mi][ni][0] = 0.f; acc[mi][ni][1] = 0.f;
      acc[mi][ni][2] = 0.f; acc[mi][ni][3] = 0.f;
    }

  for (int k0 = 0; k0 < C_; k0 += 64) {
    __syncthreads();
    #pragma unroll
    for (int j = 0; j < 4; ++j) {
      int seg = wave * 4 + j;            // 8-row segment of the 128-row tile
      int r = seg * 8 + lr;
      gload_lds16(A + (size_t)(arow0 + r) * C_ + k0 + sc * 8, As + seg * 512);
      gload_lds16(Bt + (size_t)(brow0 + r) * C_ + k0 + sc * 8, Bs + seg * 512);
    }
    __syncthreads();
    #pragma unroll
    for (int kc = 0; kc < 2; ++kc) {
      int cc = kc * 4 + lg;
      short8 af[4], bf[4];
      #pragma unroll
      for (int mi = 0; mi < 4; ++mi) {
        int m = wr * 64 + mi * 16 + ll;
        af[mi] = *(const short8*)&As[m * 64 + ((cc ^ (m & 7)) << 3)];
      }
      #pragma unroll
      for (int ni = 0; ni < 4; ++ni) {
        int n = wc * 64 + ni * 16 + ll;
        bf[ni] = *(const short8*)&Bs[n * 64 + ((cc ^ (n & 7)) << 3)];
      }
      #pragma unroll
      for (int mi = 0; mi < 4; ++mi)
        #pragma unroll
        for (int ni = 0; ni < 4; ++ni)
          acc[mi][ni] = __builtin_amdgcn_mfma_f32_16x16x32_bf16(
              af[mi], bf[ni], acc[mi][ni], 0, 0, 0);
    }
  }
}

// ---------------------------------------------------------------------------
// 64-row variant for the mixer: C[64x128] tile. (round-4 proven)
// ---------------------------------------------------------------------------
__device__ __forceinline__ void gemm_core64(
    const short* __restrict__ A, const short* __restrict__ Bt,
    int arow0, int brow0, short* As, short* Bs, float4v acc[2][4]) {
  int tid = threadIdx.x;
  int wave = tid >> 6, lane = tid & 63;
  int lr = lane >> 3, lc = lane & 7;
  int sc = lc ^ lr;                       // swizzled global chunk for staging
  int wr = wave >> 1, wc = wave & 1;
  int lg = lane >> 4, ll = lane & 15;

  #pragma unroll
  for (int mi = 0; mi < 2; ++mi)
    #pragma unroll
    for (int ni = 0; ni < 4; ++ni) {
      acc[mi][ni][0] = 0.f; acc[mi][ni][1] = 0.f;
      acc[mi][ni][2] = 0.f; acc[mi][ni][3] = 0.f;
    }

  for (int k0 = 0; k0 < C_; k0 += 64) {
    __syncthreads();
    #pragma unroll
    for (int j = 0; j < 2; ++j) {        // A: 64 rows = 8 segs of 8
      int seg = wave * 2 + j;
      int r = seg * 8 + lr;
      gload_lds16(A + (size_t)(arow0 + r) * C_ + k0 + sc * 8, As + seg * 512);
    }
    #pragma unroll
    for (int j = 0; j < 4; ++j) {        // B: 128 rows = 16 segs
      int seg = wave * 4 + j;
      int r = seg * 8 + lr;
      gload_lds16(Bt + (size_t)(brow0 + r) * C_ + k0 + sc * 8, Bs + seg * 512);
    }
    __syncthreads();
    #pragma unroll
    for (int kc = 0; kc < 2; ++kc) {
      int cc = kc * 4 + lg;
      short8 af[2], bf[4];
      #pragma unroll
      for (int mi = 0; mi < 2; ++mi) {
        int m = wr * 32 + mi * 16 + ll;
        af[mi] = *(const short8*)&As[m * 64 + ((cc ^ (m & 7)) << 3)];
      }
      #pragma unroll
      for (int ni = 0; ni < 4; ++ni) {
        int n = wc * 64 + ni * 16 + ll;
        bf[ni] = *(const short8*)&Bs[n * 64 + ((cc ^ (n & 7)) << 3)];
      }
      #pragma unroll
      for (int mi = 0; mi < 2; ++mi)
        #pragma unroll
        for (int ni = 0; ni < 4; ++ni)
          acc[mi][ni] = __builtin_amdgcn_mfma_f32_16x16x32_bf16(
              af[mi], bf[ni], acc[mi][ni], 0, 0, 0);
    }
  }
}

// ---------------------------------------------------------------------------
// QKV GEMMs, fused in grid.z: z=0 Q=x1@Wq^T, z=1 K=x2@Wk^T,
// z=2 V^T = Wv x2^T. grid=(32,8,3). LDS-staged coalesced epilogue.
// ---------------------------------------------------------------------------
__global__ __launch_bounds__(256, 3) void gemm_qkv_kernel(
    const short* __restrict__ x1b, const short* __restrict__ x2b,
    const short* __restrict__ wqt, const short* __restrict__ wkt,
    const short* __restrict__ wvt,
    short* __restrict__ qb, short* __restrict__ kb, short* __restrict__ vtb) {
  __shared__ short smem[128 * 132];       // 33792 B; As/Bs overlay + Ct
  short* As = smem;                       // 128*64 = 8192 shorts
  short* Bs = smem + 8192;                // 128*64
  int z = blockIdx.z;
  const short *A, *Bt;
  int arow0, brow0;
  if (z == 0)      { A = x1b; Bt = wqt; arow0 = blockIdx.x * 128; brow0 = blockIdx.y * 128; }
  else if (z == 1) { A = x2b; Bt = wkt; arow0 = blockIdx.x * 128; brow0 = blockIdx.y * 128; }
  else             { A = wvt; Bt = x2b; arow0 = blockIdx.y * 128; brow0 = blockIdx.x * 128; }

  float4v acc[4][4];
  gemm_core(A, Bt, arow0, brow0, As, Bs, acc);

  int tid = threadIdx.x;
  int wave = tid >> 6, lane = tid & 63;
  int wr = wave >> 1, wc = wave & 1, lg = lane >> 4, ll = lane & 15;

  __syncthreads();  // all waves done reading As/Bs; reuse smem as Ct[128][132]
  #pragma unroll
  for (int mi = 0; mi < 4; ++mi)
    #pragma unroll
    for (int ni = 0; ni < 4; ++ni)
      #pragma unroll
      for (int r2 = 0; r2 < 4; ++r2)
        smem[(wr * 64 + mi * 16 + lg * 4 + r2) * 132 + wc * 64 + ni * 16 + ll] =
            (short)f2bf(acc[mi][ni][r2]);
  __syncthreads();

  if (z <= 1) {
    short* O = (z == 0) ? qb : kb;
    int hb = brow0 >> 6;                  // n = brow0+nl -> h = hb + (nl>>6)
    #pragma unroll
    for (int p = 0; p < 8; ++p) {
      int r = p * 16 + (tid >> 4);        // local m row
      int seg = tid & 15;                 // 16B segment within the 256B row
      int m = arow0 + r, b = m >> 11, w = m & (W_ - 1);
      int half = seg >> 3, kkseg = seg & 7;
      const short* src = &smem[r * 132 + seg * 8];
      uint2 lo = *(const uint2*)src;
      uint2 hi = *(const uint2*)(src + 4);
      uint4 val; val.x = lo.x; val.y = lo.y; val.z = hi.x; val.w = hi.y;
      *(uint4*)(O + ((size_t)(b * H_ + hb + half) * W_ + w) * K_ + kkseg * 8) = val;
    }
  } else {
    int b = brow0 >> 11, w0 = brow0 & (W_ - 1);  // brow0 128-aligned -> const
    #pragma unroll
    for (int p = 0; p < 8; ++p) {
      int r = p * 16 + (tid >> 4);        // local m row (= h*64+kk space)
      int seg = tid & 15;
      int mg = arow0 + r, h = mg >> 6, kk = mg & 63;
      const short* src = &smem[r * 132 + seg * 8];
      uint2 lo = *(const uint2*)src;
      uint2 hi = *(const uint2*)(src + 4);
      uint4 val; val.x = lo.x; val.y = lo.y; val.z = hi.x; val.w = hi.y;
      *(uint4*)(vtb + ((size_t)(b * H_ + h) * K_ + kk) * W_ + w0 + seg * 8) = val;
    }
  }
}

// ---------------------------------------------------------------------------
// Mixer GEMM: out[4096,1024] fp32 = attnb @ wmb^T + bias. grid=(64,8)=512
// blocks = 2/CU. (round-4 proven; fp32 stores already 64B-coalesced)
// ---------------------------------------------------------------------------
__global__ __launch_bounds__(256, 3) void gemm_mix_kernel(
    const short* __restrict__ attnb, const short* __restrict__ wmb,
    const float* __restrict__ bias, float* __restrict__ out) {
  __shared__ short As[64 * 64], Bs[128 * 64];
  int arow0 = blockIdx.x * 64, brow0 = blockIdx.y * 128;
  float4v acc[2][4];
  gemm_core64(attnb, wmb, arow0, brow0, As, Bs, acc);

  int wave = threadIdx.x >> 6, lane = threadIdx.x & 63;
  int wr = wave >> 1, wc = wave & 1, lg = lane >> 4, ll = lane & 15;
  #pragma unroll
  for (int mi = 0; mi < 2; ++mi)
    #pragma unroll
    for (int ni = 0; ni < 4; ++ni) {
      int n = brow0 + wc * 64 + ni * 16 + ll;
      float bv = bias[n];
      #pragma unroll
      for (int r2 = 0; r2 < 4; ++r2) {
        int m = arow0 + wr * 32 + mi * 16 + lg * 4 + r2;
        out[(size_t)m * C_ + n] = acc[mi][ni][r2] + bv;
      }
    }
}

// ---------------------------------------------------------------------------
// Causal flash attention — ROUND-10 EXACT KERNEL (best measured: 43.4 us).
// 64-q tile, 1024 blocks, dual-buffered K/V, swapped-operand softmax,
// ones-MFMA lsum, max3, setprio, SINGLE barrier per key-tile iteration:
//   top:  s_waitcnt vmcnt(0) lgkmcnt(0); s_barrier; [STAGE(kt+1, cur^1)]
//   body: QK^T; bv<-Vs[cur]; mask; softmax; P; PV       (no trailing barrier)
// ---------------------------------------------------------------------------
__global__ __launch_bounds__(256, 3) void attn_mfma_kernel(
    const short* __restrict__ q, const short* __restrict__ k,
    const short* __restrict__ vt, short* __restrict__ out) {
  int bh = blockIdx.x;                    // 0..31
  int b = bh >> 4, h = bh & 15;
  int s = blockIdx.y;
  int qt = (s < 16) ? (31 - s) : (s - 16);  // balanced heavy/light pairing
  int wave = threadIdx.x >> 6;
  int lane = threadIdx.x & 63;
  int lg = lane >> 4, ll = lane & 15;

  __shared__ short Ks[2][64 * 64];        // [key][chan], swizzled chunks
  __shared__ short Vs[2][64 * 64];        // [chan][key], swizzled chunks
  __shared__ short Ps[4][16 * 72];        // per-wave P buffer [q][key(+pad)]

  const short* qp = q + (size_t)bh * W_ * K_;
  const short* kp = k + (size_t)bh * W_ * K_;
  const short* vb = vt + (size_t)bh * K_ * W_;

  // Q B-frags: this lane's q row is qt*64 + wave*16 + ll (frag col = ll)
  int qrow = qt * 64 + wave * 16 + ll;
  short8 aq[2];
  #pragma unroll
  for (int kc = 0; kc < 2; ++kc)
    aq[kc] = *(const short8*)(qp + (size_t)qrow * K_ + kc * 32 + lg * 8);

  short8 ones;                            // bf16 1.0 x8, A-frag for l-sum MFMA
  #pragma unroll
  for (int i = 0; i < 8; ++i) ones[i] = (short)0x3F80;

  float4v o[4];                           // O^T: o[ct][r] = O[q=ll][ct*16+lg*4+r]
  #pragma unroll
  for (int ct = 0; ct < 4; ++ct) {
    o[ct][0] = 0.f; o[ct][1] = 0.f; o[ct][2] = 0.f; o[ct][3] = 0.f;
  }
  float4v lsum;                           // every reg = sum_k P[q][k]
  lsum[0] = 0.f; lsum[1] = 0.f; lsum[2] = 0.f; lsum[3] = 0.f;
  float m = -INFINITY;                    // per-lane scalar running max (one q)

  int nkt = qt + 1;

  // stage key-tile kt into buffer buf (4 coalesced 16B loads per thread)
  #define STAGE(kt, buf)                                                   \
    {                                                                      \
      const short* kbase = kp + (size_t)(kt) * 64 * K_;                    \
      const short* vbase = vb + (kt) * 64;                                 \
      _Pragma("unroll")                                                    \
      for (int j = 0; j < 2; ++j) {                                        \
        int sdx = j * 256 + (int)threadIdx.x;                              \
        int mm = sdx >> 3, c7 = sdx & 7;                                   \
        int gc = c7 ^ (mm & 7);                                            \
        gload_lds16(kbase + (size_t)mm * K_ + gc * 8, &Ks[buf][sdx * 8]);  \
        gload_lds16(vbase + (size_t)mm * W_ + gc * 8, &Vs[buf][sdx * 8]);  \
      }                                                                    \
    }

  STAGE(0, 0);
  for (int kt = 0; kt < nkt; ++kt) {
    int cur = kt & 1;
    // single rendezvous per iteration: own loads landed (vmcnt 0), own LDS
    // reads drained (lgkm 0), then barrier; STAGE issues only after it.
    asm volatile("s_waitcnt vmcnt(0) lgkmcnt(0)\ns_barrier" ::: "memory");
    if (kt + 1 < nkt) STAGE(kt + 1, cur ^ 1);

    // ---- S^T = K.Q^T : st[nt][r] = S[q=ll][key = kt*64 + nt*16 + lg*4 + r]
    float4v st[4];
    __builtin_amdgcn_s_setprio(1);
    #pragma unroll
    for (int nt = 0; nt < 4; ++nt) {
      st[nt][0] = 0.f; st[nt][1] = 0.f; st[nt][2] = 0.f; st[nt][3] = 0.f;
      int n = nt * 16 + ll;               // key frag index (A operand)
      #pragma unroll
      for (int kc = 0; kc < 2; ++kc) {
        int cc = kc * 4 + lg;
        short8 bk = *(const short8*)&Ks[cur][n * 64 + ((cc ^ (n & 7)) << 3)];
        st[nt] = __builtin_amdgcn_mfma_f32_16x16x32_bf16(bk, aq[kc], st[nt], 0, 0, 0);
      }
    }
    __builtin_amdgcn_s_setprio(0);

    // ---- V^T frags (A operand of PV) ----
    short8 bv[4][2];
    #pragma unroll
    for (int ct = 0; ct < 4; ++ct) {
      int c = ct * 16 + ll;
      #pragma unroll
      for (int kc = 0; kc < 2; ++kc) {
        int cc = kc * 4 + lg;
        bv[ct][kc] = *(const short8*)&Vs[cur][c * 64 + ((cc ^ (c & 7)) << 3)];
      }
    }

    if (kt == qt) {  // diagonal tile: causal mask (key > q)
      #pragma unroll
      for (int nt = 0; nt < 4; ++nt) {
        int keyb = nt * 16 + lg * 4;      // key within tile
        #pragma unroll
        for (int r = 0; r < 4; ++r)
          if (keyb + r > wave * 16 + ll) st[nt][r] = -INFINITY;
      }
    }

    // ---- row max (per-lane scalar stats), max3-shaped tree ----
    float ma = max3f(st[0][0], st[0][1], st[0][2]);
    float mb = max3f(st[0][3], st[1][0], st[1][1]);
    float mc = max3f(st[1][2], st[1][3], st[2][0]);
    float md = max3f(st[2][1], st[2][2], st[2][3]);
    float me = max3f(st[3][0], st[3][1], st[3][2]);
    float lm = fmaxf(max3f(ma, mb, mc), max3f(md, me, st[3][3]));
    lm = fmaxf(lm, __shfl_xor(lm, 16, 64));
    lm = fmaxf(lm, __shfl_xor(lm, 32, 64));
    if (!__all(lm <= m + 8.f)) {          // defer-max: rescale only on growth
      float nm = fmaxf(m, lm);
      float al = EXP2(m - nm);            // first tile: exp2(-inf) = 0
      m = nm;
      lsum[0] *= al; lsum[1] *= al; lsum[2] *= al; lsum[3] *= al;
      #pragma unroll
      for (int ct = 0; ct < 4; ++ct) {
        o[ct][0] *= al; o[ct][1] *= al; o[ct][2] *= al; o[ct][3] *= al;
      }
    }

    // ---- P = exp2(S - m) -> bf16 (f2bf) -> wave-private LDS ----
    float p[4][4];
    #pragma unroll
    for (int nt = 0; nt < 4; ++nt)
      #pragma unroll
      for (int r = 0; r < 4; ++r)
        p[nt][r] = EXP2(st[nt][r] - m);

    short* myP = &Ps[wave][ll * 72];
    #pragma unroll
    for (int nt = 0; nt < 4; ++nt) {
      uint2 w;
      w.x = (unsigned)f2bf(p[nt][0]) | ((unsigned)f2bf(p[nt][1]) << 16);
      w.y = (unsigned)f2bf(p[nt][2]) | ((unsigned)f2bf(p[nt][3]) << 16);
      *(uint2*)(myP + nt * 16 + lg * 4) = w;
    }
    __builtin_amdgcn_s_waitcnt(0xC07F);  // lgkmcnt(0), wave-private
    short8 bp0 = *(const short8*)(myP + lg * 8);        // keys lg*8..+7
    short8 bp1 = *(const short8*)(myP + 32 + lg * 8);   // keys 32+lg*8..+7

    // ---- O^T += V^T.P^T ; l += ones.P^T (row-sum via MFMA) ----
    __builtin_amdgcn_s_setprio(1);
    lsum = __builtin_amdgcn_mfma_f32_16x16x32_bf16(ones, bp0, lsum, 0, 0, 0);
    lsum = __builtin_amdgcn_mfma_f32_16x16x32_bf16(ones, bp1, lsum, 0, 0, 0);
    #pragma unroll
    for (int ct = 0; ct < 4; ++ct) {
      o[ct] = __builtin_amdgcn_mfma_f32_16x16x32_bf16(bv[ct][0], bp0, o[ct], 0, 0, 0);
      o[ct] = __builtin_amdgcn_mfma_f32_16x16x32_bf16(bv[ct][1], bp1, o[ct], 0, 0, 0);
    }
    __builtin_amdgcn_s_setprio(0);
    // no trailing barrier: next iteration's top rendezvous fences buffer reuse
  }
  #undef STAGE

  // ---- epilogue: normalize (lane-local), write bf16 [B,W,C] as 8B packs ----
  float invl = 1.0f / lsum[0];
  size_t orow = ((size_t)(b * W_ + qrow)) * C_ + h * K_;
  #pragma unroll
  for (int ct = 0; ct < 4; ++ct) {
    uint2 w;
    w.x = (unsigned)f2bf(o[ct][0] * invl) | ((unsigned)f2bf(o[ct][1] * invl) << 16);
    w.y = (unsigned)f2bf(o[ct][2] * invl) | ((unsigned)f2bf(o[ct][3] * invl) << 16);
    *(uint2*)(out + orow + ct * 16 + lg * 4) = w;
  }
}

// ---------------------------------------------------------------------------
extern "C" void kernel_launch(void* const* d_in, const int* in_sizes, int n_in,
                              void* d_out, int out_size, void* d_ws, size_t ws_size,
                              hipStream_t stream) {
  const float* seq1  = (const float*)d_in[0];
  const float* seq2  = (const float*)d_in[1];
  const float* gamma = (const float*)d_in[2];
  const float* beta  = (const float*)d_in[3];
  const float* qp    = (const float*)d_in[4];
  const float* kp    = (const float*)d_in[5];
  const float* vp    = (const float*)d_in[6];
  const float* wm    = (const float*)d_in[7];
  const float* mb    = (const float*)d_in[8];
  float* out = (float*)d_out;

  char* ws = (char*)d_ws;
  const size_t NROW = (size_t)B_ * W_;               // 4096
  const size_t XB = NROW * C_ * sizeof(short);       // 8 MB bf16 activation buf
  const size_t WB = (size_t)C_ * C_ * sizeof(short); // 2 MB bf16 weight buf
  short* x1b = (short*)(ws);
  short* x2b = (short*)(ws + XB);
  short* qb  = (short*)(ws + 2 * XB);
  short* kb  = (short*)(ws + 3 * XB);
  short* vtb = (short*)(ws + 4 * XB);
  short* wqt = (short*)(ws + 5 * XB);
  short* wkt = (short*)(ws + 5 * XB + WB);
  short* wvt = (short*)(ws + 5 * XB + 2 * WB);
  short* wmb = (short*)(ws + 5 * XB + 3 * WB);
  short* attnb = (short*)(ws + 5 * XB + 4 * WB);

  wprep_kernel<<<dim3(C_ / 64, H_, 4), dim3(256), 0, stream>>>(
      qp, kp, vp, wm, wqt, wkt, wvt, wmb);
  ln_kernel<<<dim3(2 * (unsigned)NROW), dim3(256), 0, stream>>>(
      seq1, seq2, gamma, beta, x1b, x2b);
  gemm_qkv_kernel<<<dim3(32, 8, 3), dim3(256), 0, stream>>>(
      x1b, x2b, wqt, wkt, wvt, qb, kb, vtb);
  attn_mfma_kernel<<<dim3(32, 32), dim3(256), 0, stream>>>(
      qb, kb, vtb, attnb);
  gemm_mix_kernel<<<dim3(64, 8), dim3(256), 0, stream>>>(attnb, wmb, mb, out);
}